// Round 11
// baseline (563.039 us; speedup 1.0000x reference)
//
#include <hip/hip_runtime.h>
#include <hip/hip_bf16.h>

// PositionalEncoding: out[b,c,w1,w2,t] = x[b,c,w1,w2,t] + pe[c,t]
//   pe[c,t] = (c even) ? sin(inv_freq[c]*t) : cos(inv_freq[c]*t)
//   inv_freq[c] = 10000^(-2*(c/2)/C)
// Shapes: B=4, C=64, W=128, T=20 -> 83,886,080 fp32 elements, ~671 MB traffic.
//
// Mapping: thread <-> one float4 position within a batch slab (fixed c, t0),
// unrolled over b=0..3. PE for the 4 t-values is computed once per thread in
// registers -> no LDS, no per-iteration div/mod, 4 independent loads in flight.

#define C_DIM 64
#define T_DIM 20
#define W_DIM 128
#define CSTRIDE (W_DIM * W_DIM * T_DIM)     // 327,680 elems per channel slab
#define BSTRIDE (C_DIM * CSTRIDE)           // 20,971,520 elems per batch
#define PER_B_V4 (BSTRIDE / 4)              // 5,242,880 float4s per batch
#define BLOCKS (PER_B_V4 / 256)             // 20,480 — exact fit, no guard

typedef float f32x4 __attribute__((ext_vector_type(4)));

__global__ __launch_bounds__(256) void pe_add_kernel(const float* __restrict__ x,
                                                     float* __restrict__ out) {
    unsigned j = blockIdx.x * 256u + threadIdx.x;   // float4 index within batch slab
    unsigned i0 = j * 4u;                           // element index within batch slab
    unsigned c = i0 / (unsigned)CSTRIDE;            // channel (uniform per ~1280 blocks)
    unsigned t0 = i0 % (unsigned)T_DIM;             // in {0,4,8,12,16}; float4 never crosses a T-row

    // pe[c, t0..t0+3] in registers, computed once
    float invf = __powf(10000.0f, -2.0f * (float)(c >> 1) * (1.0f / 64.0f));
    float a0 = invf * (float)t0;
    f32x4 p;
    if (c & 1) {
        p.x = cosf(a0);
        p.y = cosf(a0 + invf);
        p.z = cosf(a0 + 2.0f * invf);
        p.w = cosf(a0 + 3.0f * invf);
    } else {
        p.x = sinf(a0);
        p.y = sinf(a0 + invf);
        p.z = sinf(a0 + 2.0f * invf);
        p.w = sinf(a0 + 3.0f * invf);
    }

    const f32x4* __restrict__ x4 = (const f32x4*)x;
    f32x4* __restrict__ o4 = (f32x4*)out;

    // 4 independent loads issued up front (MLP=4), then add + nt-store.
    f32x4 v0 = x4[j + 0u * PER_B_V4];
    f32x4 v1 = x4[j + 1u * PER_B_V4];
    f32x4 v2 = x4[j + 2u * PER_B_V4];
    f32x4 v3 = x4[j + 3u * PER_B_V4];

    v0 += p;
    v1 += p;
    v2 += p;
    v3 += p;

    __builtin_nontemporal_store(v0, &o4[j + 0u * PER_B_V4]);
    __builtin_nontemporal_store(v1, &o4[j + 1u * PER_B_V4]);
    __builtin_nontemporal_store(v2, &o4[j + 2u * PER_B_V4]);
    __builtin_nontemporal_store(v3, &o4[j + 3u * PER_B_V4]);
}

extern "C" void kernel_launch(void* const* d_in, const int* in_sizes, int n_in,
                              void* d_out, int out_size, void* d_ws, size_t ws_size,
                              hipStream_t stream) {
    const float* x = (const float*)d_in[0];
    float* out = (float*)d_out;
    pe_add_kernel<<<BLOCKS, 256, 0, stream>>>(x, out);
}